// Round 9
// baseline (3289.009 us; speedup 1.0000x reference)
//
#include <hip/hip_runtime.h>
#include <hip/hip_bf16.h>

#define B 64
#define T 256
#define IN 512
#define H 1024
#define L 6

#define NBLK 192            // 6 layers * 32 col tiles
#define TPB 256             // 4 waves, 1 wave/SIMD (high VGPR)
#define NCOL 32
#define TILES_PER_L 32
#define BUFB 32768          // one A buffer: 64 rows x 512 B

typedef __bf16 bf16x8 __attribute__((ext_vector_type(8)));
typedef __bf16 bf16x4 __attribute__((ext_vector_type(4)));
typedef float f32x4 __attribute__((ext_vector_type(4)));

// ---------------------------------------------------------------------------
// prep: x [B,T,I] fp32 -> xbf [T,B,I] bf16 ; h0 fp32 -> hb0 bf16
// ---------------------------------------------------------------------------
__global__ void prep_kernel(const float* __restrict__ x,
                            const float* __restrict__ h0,
                            __bf16* __restrict__ xbf,
                            __bf16* __restrict__ hb0) {
    const int N4x = B * T * (IN / 4);
    const int N4h = L * B * (H / 4);
    int stride = gridDim.x * blockDim.x;
    for (int u = blockIdx.x * blockDim.x + threadIdx.x; u < N4x + N4h; u += stride) {
        if (u < N4x) {
            int b = u / (T * (IN / 4));
            int r = u % (T * (IN / 4));
            int t = r / (IN / 4), c4 = r % (IN / 4);
            float4 v = reinterpret_cast<const float4*>(x)[u];
            bf16x4 o = {(__bf16)v.x, (__bf16)v.y, (__bf16)v.z, (__bf16)v.w};
            *reinterpret_cast<bf16x4*>(xbf + ((size_t)t * B + b) * IN + c4 * 4) = o;
        } else {
            int j = u - N4x;
            float4 v = reinterpret_cast<const float4*>(h0)[j];
            bf16x4 o = {(__bf16)v.x, (__bf16)v.y, (__bf16)v.z, (__bf16)v.w};
            *reinterpret_cast<bf16x4*>(hb0 + (size_t)j * 4) = o;
        }
    }
}

// ---------------------------------------------------------------------------
// Persistent per-(layer, col-tile) kernel. 4 waves; W in VGPRs (48 bf16x8 per
// lane, gathered once). LDS = 2 x 32 KB A double-buffer (static, swizzled).
// h + flags via Infinity Cache (sc0 sc1); x via cached loads (read-only).
// All 32 h-load quads use DISTINCT registers (no WAR on async dests).
// ---------------------------------------------------------------------------
__global__ __launch_bounds__(TPB, 1)
void rnn_kernel(const __bf16* __restrict__ xbf,   // [T][B][IN]
                const float*  __restrict__ wih,   // [L][H][IN] fp32
                const float*  __restrict__ whh,   // [L][H][H]  fp32
                const float*  __restrict__ bih,
                const float*  __restrict__ bhh,
                __bf16* __restrict__ hb0,         // [L][B][H]
                __bf16* __restrict__ hb1,
                float*  __restrict__ out,
                unsigned* __restrict__ flags) {   // [L*32]
    __shared__ char smem[2 * BUFB];               // 64 KB static

    const int l    = blockIdx.x >> 5;
    const int rank = blockIdx.x & 31;
    const int n0   = rank * NCOL;
    const int tid  = threadIdx.x;
    const int lane = tid & 63;
    const int wave = tid >> 6;
    const int mw   = wave & 1;     // row half: rows mw*32..+31
    const int nw   = wave >> 1;    // col half: cols n0+nw*16..+15
    const int lr   = lane & 15;
    const int lk   = lane >> 4;

    const int g = n0 + nw * 16 + lr;              // output column
    const float bv = bih[l * H + g] + bhh[l * H + g];

    // ---- one-time: this lane's 48 W fragments -> VGPRs ---------------------
    bf16x8 w[48];
    #pragma unroll
    for (int s = 0; s < 48; ++s) {
        const float* src = (s < 16)
            ? wih + ((size_t)(l * H + g)) * IN + s * 32 + lk * 8
            : whh + ((size_t)(l * H + g)) * H + (s - 16) * 32 + lk * 8;
        float4 f0 = *reinterpret_cast<const float4*>(src);
        float4 f1 = *reinterpret_cast<const float4*>(src + 4);
        w[s] = bf16x8{(__bf16)f0.x, (__bf16)f0.y, (__bf16)f0.z, (__bf16)f0.w,
                      (__bf16)f1.x, (__bf16)f1.y, (__bf16)f1.z, (__bf16)f1.w};
    }

    const int srow  = tid >> 2;    // staging row 0..63
    const int ubase = tid & 3;     // staging 128B segment
    const int sx    = srow & 7;    // swizzle key

#define VMWAIT(N) do { asm volatile("s_waitcnt vmcnt(" #N ")" ::: "memory");    \
                       __builtin_amdgcn_sched_barrier(0); } while (0)

#define ISSUE8(P, D0,D1,D2,D3,D4,D5,D6,D7)                                      \
    asm volatile(                                                               \
        "global_load_dwordx4 %[d0], %[a], off sc0 sc1\n\t"                      \
        "global_load_dwordx4 %[d1], %[a], off offset:16 sc0 sc1\n\t"            \
        "global_load_dwordx4 %[d2], %[a], off offset:32 sc0 sc1\n\t"            \
        "global_load_dwordx4 %[d3], %[a], off offset:48 sc0 sc1\n\t"            \
        "global_load_dwordx4 %[d4], %[a], off offset:64 sc0 sc1\n\t"            \
        "global_load_dwordx4 %[d5], %[a], off offset:80 sc0 sc1\n\t"            \
        "global_load_dwordx4 %[d6], %[a], off offset:96 sc0 sc1\n\t"            \
        "global_load_dwordx4 %[d7], %[a], off offset:112 sc0 sc1"               \
        : [d0]"=&v"(D0), [d1]"=&v"(D1), [d2]"=&v"(D2), [d3]"=&v"(D3),           \
          [d4]"=&v"(D4), [d5]"=&v"(D5), [d6]"=&v"(D6), [d7]"=&v"(D7)            \
        : [a]"v"(P) : "memory")

    // LDS stores: clean char* arithmetic, XOR on integer index -> ds_write
#define WRITE8(BOFF, D0,D1,D2,D3,D4,D5,D6,D7)                                   \
    { char* rb_ = smem + (BOFF) + srow * 512;                                   \
      *reinterpret_cast<f32x4*>(rb_ + (((ubase*8+0) ^ sx) << 4)) = D0;          \
      *reinterpret_cast<f32x4*>(rb_ + (((ubase*8+1) ^ sx) << 4)) = D1;          \
      *reinterpret_cast<f32x4*>(rb_ + (((ubase*8+2) ^ sx) << 4)) = D2;          \
      *reinterpret_cast<f32x4*>(rb_ + (((ubase*8+3) ^ sx) << 4)) = D3;          \
      *reinterpret_cast<f32x4*>(rb_ + (((ubase*8+4) ^ sx) << 4)) = D4;          \
      *reinterpret_cast<f32x4*>(rb_ + (((ubase*8+5) ^ sx) << 4)) = D5;          \
      *reinterpret_cast<f32x4*>(rb_ + (((ubase*8+6) ^ sx) << 4)) = D6;          \
      *reinterpret_cast<f32x4*>(rb_ + (((ubase*8+7) ^ sx) << 4)) = D7; }

    // x staging via cached C++ loads (x is read-only -> L2 is safe)
#define STAGE_XC(SRCC, KOFF, BOFF)                                              \
    { _Pragma("unroll")                                                         \
      for (int j = 0; j < 8; ++j) {                                             \
          f32x4 v = *reinterpret_cast<const f32x4*>(                            \
              (SRCC) + srow * 1024 + (KOFF) + ubase * 128 + j * 16);            \
          *reinterpret_cast<f32x4*>(smem + (BOFF) + srow * 512                  \
              + (((ubase * 8 + j) ^ sx) << 4)) = v;                             \
      } }

    // 16 MFMAs: 2 row-frags x 8 k-slices; W from regs, A from swizzled LDS
#define MFMA_CH(BOFF, SB, ACC)                                                  \
    { _Pragma("unroll")                                                         \
      for (int fi = 0; fi < 2; ++fi) {                                          \
          const int ar_ = mw * 32 + fi * 16 + lr;                               \
          const int ax_ = ar_ & 7;                                              \
          _Pragma("unroll")                                                     \
          for (int ss = 0; ss < 8; ++ss) {                                      \
              bf16x8 af = *reinterpret_cast<const bf16x8*>(                     \
                  smem + (BOFF) + ar_ * 512 + ((((ss << 2) | lk) ^ ax_) << 4)); \
              ACC[fi][ss & 1] = __builtin_amdgcn_mfma_f32_16x16x32_bf16(        \
                  af, w[(SB) + ss], ACC[fi][ss & 1], 0, 0, 0);                  \
          } } }

    // 32 distinct quads for the 4 h chunks (written once per step each)
    f32x4 qa0,qa1,qa2,qa3,qa4,qa5,qa6,qa7;
    f32x4 qb0,qb1,qb2,qb3,qb4,qb5,qb6,qb7;
    f32x4 qc0,qc1,qc2,qc3,qc4,qc5,qc6,qc7;
    f32x4 qd0,qd1,qd2,qd3,qd4,qd5,qd6,qd7;
    f32x4 hacc[2][2];
    const f32x4 zero = {0.f, 0.f, 0.f, 0.f};
    #pragma unroll
    for (int fi = 0; fi < 2; ++fi) { hacc[fi][0] = zero; hacc[fi][1] = zero; }

    // ---- prologue: x-projection for t=0 ------------------------------------
    {
        const char* xc0 = (const char*)xbf;
        STAGE_XC(xc0, 0, 0);
        __syncthreads();
        MFMA_CH(0, 0, hacc);
        STAGE_XC(xc0, 512, BUFB);
        __syncthreads();
        MFMA_CH(BUFB, 8, hacc);
    }

    for (int t = 0; t < T; ++t) {
        const __bf16* hcur = (t & 1) ? hb1 : hb0;
        __bf16*       hnxt = (t & 1) ? hb0 : hb1;

        // P: wave0 polls all 32 sibling flags (IF-scope, fused load+wait)
        if (t > 0 && wave == 0) {
            const unsigned* fa = flags + l * TILES_PER_L + (lane & 31);
            unsigned f;
            for (;;) {
                asm volatile("global_load_dword %0, %1, off sc0 sc1\n\t"
                             "s_waitcnt vmcnt(0)"
                             : "=&v"(f) : "v"(fa) : "memory");
                if (__all((int)(f >= (unsigned)t))) break;
                __builtin_amdgcn_s_sleep(1);
            }
        }
        __syncthreads();   // P-bar

        // ---- issue ALL 32 h quad loads (IF-coherent), distinct registers ---
        const char* hq = (const char*)(hcur + (size_t)l * B * H)
                       + srow * 2048 + ubase * 128;
        ISSUE8(hq,        qa0,qa1,qa2,qa3,qa4,qa5,qa6,qa7);
        ISSUE8(hq + 512,  qb0,qb1,qb2,qb3,qb4,qb5,qb6,qb7);
        ISSUE8(hq + 1024, qc0,qc1,qc2,qc3,qc4,qc5,qc6,qc7);
        ISSUE8(hq + 1536, qd0,qd1,qd2,qd3,qd4,qd5,qd6,qd7);

        VMWAIT(24); WRITE8(0,    qa0,qa1,qa2,qa3,qa4,qa5,qa6,qa7);
        __syncthreads();
        MFMA_CH(0, 16, hacc);
        VMWAIT(16); WRITE8(BUFB, qb0,qb1,qb2,qb3,qb4,qb5,qb6,qb7);
        __syncthreads();
        MFMA_CH(BUFB, 24, hacc);
        VMWAIT(8);  WRITE8(0,    qc0,qc1,qc2,qc3,qc4,qc5,qc6,qc7);
        __syncthreads();
        MFMA_CH(0, 32, hacc);
        VMWAIT(0);  WRITE8(BUFB, qd0,qd1,qd2,qd3,qd4,qd5,qd6,qd7);
        __syncthreads();
        MFMA_CH(BUFB, 40, hacc);

        // ---- epilogue: bias + leaky; h-stores (IF); out; drain; signal -----
        float vv[8];
        #pragma unroll
        for (int fi = 0; fi < 2; ++fi)
            #pragma unroll
            for (int j = 0; j < 4; ++j) {
                float v = hacc[fi][0][j] + hacc[fi][1][j] + bv;
                vv[fi * 4 + j] = (v >= 0.f) ? v : 0.01f * v;
            }
        {
            union { __bf16 b; unsigned short u; } cv;
            uint32_t s0,s1,s2,s3,s4,s5,s6,s7;
            cv.b = (__bf16)vv[0]; s0 = cv.u;  cv.b = (__bf16)vv[1]; s1 = cv.u;
            cv.b = (__bf16)vv[2]; s2 = cv.u;  cv.b = (__bf16)vv[3]; s3 = cv.u;
            cv.b = (__bf16)vv[4]; s4 = cv.u;  cv.b = (__bf16)vv[5]; s5 = cv.u;
            cv.b = (__bf16)vv[6]; s6 = cv.u;  cv.b = (__bf16)vv[7]; s7 = cv.u;
            const char* p0 = (const char*)(hnxt
                              + ((size_t)(l * B + mw * 32 + lk * 4)) * H + g);
            const char* p1 = p0 + 4096;      // rows +2,+3
            const char* p2 = p0 + 32768;     // fi=1: +16 rows
            const char* p3 = p2 + 4096;
            asm volatile(
                "global_store_short %[a0], %[v0], off sc0 sc1\n\t"
                "global_store_short %[a0], %[v1], off offset:2048 sc0 sc1\n\t"
                "global_store_short %[a1], %[v2], off sc0 sc1\n\t"
                "global_store_short %[a1], %[v3], off offset:2048 sc0 sc1\n\t"
                "global_store_short %[a2], %[v4], off sc0 sc1\n\t"
                "global_store_short %[a2], %[v5], off offset:2048 sc0 sc1\n\t"
                "global_store_short %[a3], %[v6], off sc0 sc1\n\t"
                "global_store_short %[a3], %[v7], off offset:2048 sc0 sc1"
                :: [a0]"v"(p0), [a1]"v"(p1), [a2]"v"(p2), [a3]"v"(p3),
                   [v0]"v"(s0), [v1]"v"(s1), [v2]"v"(s2), [v3]"v"(s3),
                   [v4]"v"(s4), [v5]"v"(s5), [v6]"v"(s6), [v7]"v"(s7)
                : "memory");
        }
        #pragma unroll
        for (int fi = 0; fi < 2; ++fi)
            #pragma unroll
            for (int j = 0; j < 4; ++j) {
                int b = mw * 32 + fi * 16 + lk * 4 + j;
                if (l == L - 1) out[((size_t)b * T + t) * H + g] = vv[fi * 4 + j];
                if (t == T - 1)
                    out[(size_t)B * T * H + ((size_t)(l * B + b)) * H + g]
                        = vv[fi * 4 + j];
            }
        VMWAIT(0);         // h stores at IF
        __syncthreads();   // whole block done
        if (tid == 0) {
            unsigned val = (unsigned)(t + 1);
            unsigned* fp = flags + l * TILES_PER_L + rank;
            asm volatile("global_store_dword %0, %1, off sc0 sc1"
                         :: "v"(fp), "v"(val) : "memory");
        }

        // ---- x-projection for t+1 directly into (reset) hacc ---------------
        if (t + 1 < T) {
            #pragma unroll
            for (int fi = 0; fi < 2; ++fi) { hacc[fi][0] = zero; hacc[fi][1] = zero; }
            const char* xn = (const char*)(xbf + (size_t)(t + 1) * B * IN);
            STAGE_XC(xn, 0, 0);
            __syncthreads();
            MFMA_CH(0, 0, hacc);
            STAGE_XC(xn, 512, BUFB);
            __syncthreads();
            MFMA_CH(BUFB, 8, hacc);
        }
    }
}

// ---------------------------------------------------------------------------
extern "C" void kernel_launch(void* const* d_in, const int* in_sizes, int n_in,
                              void* d_out, int out_size, void* d_ws, size_t ws_size,
                              hipStream_t stream) {
    const float* x   = (const float*)d_in[0];
    const float* h0  = (const float*)d_in[1];
    const float* wih = (const float*)d_in[2];
    const float* whh = (const float*)d_in[3];
    const float* bih = (const float*)d_in[4];
    const float* bhh = (const float*)d_in[5];
    float* out = (float*)d_out;

    char* ws = (char*)d_ws;
    __bf16* xbf = (__bf16*)ws;                                   // 16 MB
    __bf16* hb0 = (__bf16*)(ws + (size_t)16777216);              // 768 KB
    __bf16* hb1 = (__bf16*)(ws + (size_t)16777216 + 786432);     // 768 KB
    unsigned* flags = (unsigned*)(ws + (size_t)16777216 + 2 * 786432); // 768 B

    hipMemsetAsync(flags, 0, L * TILES_PER_L * sizeof(unsigned), stream);
    prep_kernel<<<2048, 256, 0, stream>>>(x, h0, xbf, hb0);

    rnn_kernel<<<NBLK, TPB, 0, stream>>>(
        xbf, wih, whh, bih, bhh, hb0, hb1, out, flags);
}

// Round 11
// 2084.250 us; speedup vs baseline: 1.5780x; 1.5780x over previous
//
#include <hip/hip_runtime.h>
#include <hip/hip_bf16.h>

#define B 64
#define T 256
#define IN 512
#define H 1024
#define L 6

#define NBLK 192            // 6 layers * 32 col tiles
#define TPB 512             // 8 waves = 2 row-tiles x 4 K-slices
#define NCOL 32
#define TILES_PER_L 32
#define BUFB 32768          // one frag-major A chunk buffer (K=256)

typedef __bf16 bf16x8 __attribute__((ext_vector_type(8)));
typedef __bf16 bf16x4 __attribute__((ext_vector_type(4)));
typedef float f32x4  __attribute__((ext_vector_type(4)));
typedef float f32x16 __attribute__((ext_vector_type(16)));

// ---------------------------------------------------------------------------
// prep: x [B,T,I] fp32 -> xbf [T,B,I] bf16 ; h0 fp32 -> hb0 bf16
// ---------------------------------------------------------------------------
__global__ void prep_kernel(const float* __restrict__ x,
                            const float* __restrict__ h0,
                            __bf16* __restrict__ xbf,
                            __bf16* __restrict__ hb0) {
    const int N4x = B * T * (IN / 4);
    const int N4h = L * B * (H / 4);
    int stride = gridDim.x * blockDim.x;
    for (int u = blockIdx.x * blockDim.x + threadIdx.x; u < N4x + N4h; u += stride) {
        if (u < N4x) {
            int b = u / (T * (IN / 4));
            int r = u % (T * (IN / 4));
            int t = r / (IN / 4), c4 = r % (IN / 4);
            float4 v = reinterpret_cast<const float4*>(x)[u];
            bf16x4 o = {(__bf16)v.x, (__bf16)v.y, (__bf16)v.z, (__bf16)v.w};
            *reinterpret_cast<bf16x4*>(xbf + ((size_t)t * B + b) * IN + c4 * 4) = o;
        } else {
            int j = u - N4x;
            float4 v = reinterpret_cast<const float4*>(h0)[j];
            bf16x4 o = {(__bf16)v.x, (__bf16)v.y, (__bf16)v.z, (__bf16)v.w};
            *reinterpret_cast<bf16x4*>(hb0 + (size_t)j * 4) = o;
        }
    }
}

// ---------------------------------------------------------------------------
// Persistent per-(layer, col-tile) kernel. 8 waves = (th: 2 row-tiles of 32)
// x (ks: 4 K-slices). mfma 32x32x16; W in VGPRs (24 frags = 96 VGPR/lane,
// per-wave K-slice); A staged frag-major in LDS (2 x 32KB dbuf, XOR-swizzled);
// K-split partials reduced through LDS. h + flags via IF (sc0 sc1), r7 proto.
// ---------------------------------------------------------------------------
__global__ __launch_bounds__(TPB, 2)
void rnn_kernel(const __bf16* __restrict__ xbf,   // [T][B][IN]
                const float*  __restrict__ wih,   // [L][H][IN] fp32
                const float*  __restrict__ whh,   // [L][H][H]  fp32
                const float*  __restrict__ bih,
                const float*  __restrict__ bhh,
                __bf16* __restrict__ hb0,         // [L][B][H]
                __bf16* __restrict__ hb1,
                float*  __restrict__ out,
                unsigned* __restrict__ flags) {   // [L*32]
    __shared__ char smem[2 * BUFB];               // 64 KB static

    const int l    = blockIdx.x >> 5;
    const int rank = blockIdx.x & 31;
    const int n0   = rank * NCOL;
    const int tid  = threadIdx.x;
    const int lane = tid & 63;
    const int wave = tid >> 6;
    const int th   = wave & 1;      // row tile: rows th*32 .. +31
    const int ks   = wave >> 1;     // K-slice 0..3
    const int l31  = lane & 31;
    const int l5   = lane >> 5;
    const int hi8  = l5 * 8;

    const int g = n0 + l31;                       // output column
    const float bv = bih[l * H + g] + bhh[l * H + g];

    // ---- one-time: this wave's 24 W B-frags -> VGPRs (cached loads) --------
    // B-frag layout (32x32x16): lane holds W[col=n0+l31][k = kbase + (l>>5)*8 + j]
    bf16x8 w[24];
    #pragma unroll
    for (int f = 0; f < 8; ++f) {                 // x-part: 8 frags (K=128 slice)
        int kg = (ks & 1) * 256 + (ks >> 1) * 128 + f * 16 + hi8;
        const float* s = wih + ((size_t)(l * H + g)) * IN + kg;
        float4 a = *reinterpret_cast<const float4*>(s);
        float4 b = *reinterpret_cast<const float4*>(s + 4);
        w[f] = bf16x8{(__bf16)a.x, (__bf16)a.y, (__bf16)a.z, (__bf16)a.w,
                      (__bf16)b.x, (__bf16)b.y, (__bf16)b.z, (__bf16)b.w};
    }
    #pragma unroll
    for (int k2 = 0; k2 < 16; ++k2) {             // h-part: 16 frags (K=256 slice)
        int kg = ks * 256 + k2 * 16 + hi8;
        const float* s = whh + ((size_t)(l * H + g)) * H + kg;
        float4 a = *reinterpret_cast<const float4*>(s);
        float4 b = *reinterpret_cast<const float4*>(s + 4);
        w[8 + k2] = bf16x8{(__bf16)a.x, (__bf16)a.y, (__bf16)a.z, (__bf16)a.w,
                           (__bf16)b.x, (__bf16)b.y, (__bf16)b.z, (__bf16)b.w};
    }

    // ---- staging geometry: thread owns row=tid>>3, 64B seg=tid&7 -----------
    const int row = tid >> 3;
    const int seg = tid & 7;
    // LDS write offsets for quads n=0..3 (frag-major slot, XOR-swizzled)
    int wo0, wo1, wo2, wo3;
    {
        int r5 = (row >> 5) * 64, r31w = row & 31;
        #define MKWO(N, DST) { int qc = seg * 4 + (N);                          \
            int kk = qc >> 1, hi = qc & 1;                                      \
            int S = kk * 128 + r5 + hi * 32 + r31w;                             \
            DST = ((S ^ (kk & 7)) << 4); }
        MKWO(0, wo0) MKWO(1, wo1) MKWO(2, wo2) MKWO(3, wo3)
        #undef MKWO
    }
    const int rbo = th * 1024 + l5 * 512;         // frag read base

#define VMWAIT(N) do { asm volatile("s_waitcnt vmcnt(" #N ")" ::: "memory");    \
                       __builtin_amdgcn_sched_barrier(0); } while (0)

#define HISSUE(PTR, D0,D1,D2,D3)                                                \
    asm volatile(                                                               \
        "global_load_dwordx4 %[d0], %[a], off sc0 sc1\n\t"                      \
        "global_load_dwordx4 %[d1], %[a], off offset:16 sc0 sc1\n\t"            \
        "global_load_dwordx4 %[d2], %[a], off offset:32 sc0 sc1\n\t"            \
        "global_load_dwordx4 %[d3], %[a], off offset:48 sc0 sc1"                \
        : [d0]"=&v"(D0), [d1]"=&v"(D1), [d2]"=&v"(D2), [d3]"=&v"(D3)            \
        : [a]"v"(PTR) : "memory")

#define LWRITE(BOFF, D0,D1,D2,D3)                                               \
    { char* lw_ = smem + (BOFF);                                                \
      *reinterpret_cast<f32x4*>(lw_ + wo0) = D0;                                \
      *reinterpret_cast<f32x4*>(lw_ + wo1) = D1;                                \
      *reinterpret_cast<f32x4*>(lw_ + wo2) = D2;                                \
      *reinterpret_cast<f32x4*>(lw_ + wo3) = D3; }

    // cached x staging (read-only data): chunk c at bytes c*512 of each row
#define XSTAGE(XBASE, C, BOFF)                                                  \
    { const char* xp_ = (XBASE) + row * 1024 + (C) * 512 + seg * 64;            \
      f32x4 xa_ = *reinterpret_cast<const f32x4*>(xp_);                         \
      f32x4 xb_ = *reinterpret_cast<const f32x4*>(xp_ + 16);                    \
      f32x4 xc_ = *reinterpret_cast<const f32x4*>(xp_ + 32);                    \
      f32x4 xd_ = *reinterpret_cast<const f32x4*>(xp_ + 48);                    \
      LWRITE(BOFF, xa_, xb_, xc_, xd_); }

    // h-chunk C: computed by the 2 waves with ks==C (16 mfma, kk2 0..15)
#define MFMA_H(C, BOFF)                                                         \
    if (ks == (C)) { _Pragma("unroll")                                          \
      for (int kk2 = 0; kk2 < 16; ++kk2) {                                      \
          bf16x8 af = *reinterpret_cast<const bf16x8*>(                         \
              smem + (BOFF) + rbo + kk2 * 2048 + ((l31 ^ (kk2 & 7)) << 4));     \
          if (kk2 & 1) accO = __builtin_amdgcn_mfma_f32_32x32x16_bf16(          \
                                  af, w[8 + kk2], accO, 0, 0, 0);               \
          else         accE = __builtin_amdgcn_mfma_f32_32x32x16_bf16(          \
                                  af, w[8 + kk2], accE, 0, 0, 0);               \
      } }

    // x-chunk C: computed by 4 waves with (ks&1)==C, kk-half (ks>>1)
#define MFMA_X(C, BOFF)                                                         \
    if ((ks & 1) == (C)) { const int kb_ = (ks >> 1) * 16384;                   \
      _Pragma("unroll")                                                         \
      for (int f2 = 0; f2 < 8; ++f2) {                                          \
          bf16x8 af = *reinterpret_cast<const bf16x8*>(                         \
              smem + (BOFF) + rbo + kb_ + f2 * 2048 + ((l31 ^ f2) << 4));       \
          if (f2 & 1) accO = __builtin_amdgcn_mfma_f32_32x32x16_bf16(           \
                                 af, w[f2], accO, 0, 0, 0);                     \
          else        accE = __builtin_amdgcn_mfma_f32_32x32x16_bf16(           \
                                 af, w[f2], accE, 0, 0, 0);                     \
      } }

    f32x16 accE, accO;
    #pragma unroll
    for (int i = 0; i < 16; ++i) { accE[i] = 0.f; accO[i] = 0.f; }

    f32x4 qa0,qa1,qa2,qa3, qb0,qb1,qb2,qb3, qc0,qc1,qc2,qc3, qd0,qd1,qd2,qd3;

    // ---- prologue: x-projection for t=0 ------------------------------------
    {
        const char* xb0 = (const char*)xbf;
        XSTAGE(xb0, 0, 0);
        __syncthreads();
        MFMA_X(0, 0);
        XSTAGE(xb0, 1, BUFB);
        __syncthreads();
        MFMA_X(1, BUFB);
    }

    for (int t = 0; t < T; ++t) {
        const __bf16* hcur = (t & 1) ? hb1 : hb0;
        __bf16*       hnxt = (t & 1) ? hb0 : hb1;

        // P: wave0 polls all 32 sibling flags (IF-scope)
        if (t > 0 && wave == 0) {
            const unsigned* fa = flags + l * TILES_PER_L + (lane & 31);
            unsigned f;
            for (;;) {
                asm volatile("global_load_dword %0, %1, off sc0 sc1\n\t"
                             "s_waitcnt vmcnt(0)"
                             : "=&v"(f) : "v"(fa) : "memory");
                if (__all((int)(f >= (unsigned)t))) break;
                __builtin_amdgcn_s_sleep(1);
            }
        }
        __syncthreads();   // BAR_P (also protects buffer reuse vs x-phase)

        // ---- issue all 16 h quads (4 chunks), IF-coherent ------------------
        const char* hq = (const char*)(hcur + (size_t)l * B * H)
                       + row * 2048 + seg * 64;
        HISSUE(hq,        qa0,qa1,qa2,qa3);
        HISSUE(hq + 512,  qb0,qb1,qb2,qb3);
        HISSUE(hq + 1024, qc0,qc1,qc2,qc3);
        HISSUE(hq + 1536, qd0,qd1,qd2,qd3);

        VMWAIT(12); LWRITE(0,    qa0,qa1,qa2,qa3);
        __syncthreads();                            // BAR1: c0 staged
        MFMA_H(0, 0);
        VMWAIT(8);  LWRITE(BUFB, qb0,qb1,qb2,qb3);
        __syncthreads();                            // BAR2: c1 staged, c0 done
        MFMA_H(1, BUFB);
        VMWAIT(4);  LWRITE(0,    qc0,qc1,qc2,qc3);
        __syncthreads();                            // BAR3
        MFMA_H(2, 0);
        VMWAIT(0);  LWRITE(BUFB, qd0,qd1,qd2,qd3);
        __syncthreads();                            // BAR4
        MFMA_H(3, BUFB);

        // ---- K-split reduction through LDS (region = bufA) -----------------
        {
            f32x16 pw = accE + accO;
            char* pp = smem + wave * 4096 + lane * 16;
            *reinterpret_cast<f32x4*>(pp)        = f32x4{pw[0],pw[1],pw[2],pw[3]};
            *reinterpret_cast<f32x4*>(pp + 1024) = f32x4{pw[4],pw[5],pw[6],pw[7]};
            *reinterpret_cast<f32x4*>(pp + 2048) = f32x4{pw[8],pw[9],pw[10],pw[11]};
            *reinterpret_cast<f32x4*>(pp + 3072) = f32x4{pw[12],pw[13],pw[14],pw[15]};
        }
        __syncthreads();                            // BAR5: partials visible
        f32x4 fv;
        {
            const char* rp = smem + th * 4096 + ks * 1024 + lane * 16;
            f32x4 p0 = *reinterpret_cast<const f32x4*>(rp);
            f32x4 p1 = *reinterpret_cast<const f32x4*>(rp + 8192);
            f32x4 p2 = *reinterpret_cast<const f32x4*>(rp + 16384);
            f32x4 p3 = *reinterpret_cast<const f32x4*>(rp + 24576);
            fv = p0 + p1 + p2 + p3;
        }

        // ---- epilogue: bias + leaky; this wave owns rows rbase..+3 ---------
        // C/D 32x32: col=lane&31, row=(reg&3)+8*(reg>>2)+4*(lane>>5); reg=ks*4+j
        const int rbase = 8 * ks + 4 * l5 + 32 * th;
        float vv[4];
        #pragma unroll
        for (int j = 0; j < 4; ++j) {
            float v = fv[j] + bv;
            vv[j] = (v >= 0.f) ? v : 0.01f * v;
        }
        {
            union { __bf16 b; unsigned short u; } cv;
            uint32_t s0, s1, s2, s3;
            cv.b = (__bf16)vv[0]; s0 = cv.u;
            cv.b = (__bf16)vv[1]; s1 = cv.u;
            cv.b = (__bf16)vv[2]; s2 = cv.u;
            cv.b = (__bf16)vv[3]; s3 = cv.u;
            const char* p0 = (const char*)(hnxt + ((size_t)(l * B + rbase)) * H + g);
            const char* p1 = p0 + 4096;   // rows +2,+3 (13-bit signed imm limit)
            asm volatile(
                "global_store_short %[a0], %[v0], off sc0 sc1\n\t"
                "global_store_short %[a0], %[v1], off offset:2048 sc0 sc1\n\t"
                "global_store_short %[a1], %[v2], off sc0 sc1\n\t"
                "global_store_short %[a1], %[v3], off offset:2048 sc0 sc1"
                :: [a0]"v"(p0), [a1]"v"(p1),
                   [v0]"v"(s0), [v1]"v"(s1), [v2]"v"(s2), [v3]"v"(s3)
                : "memory");
        }
        #pragma unroll
        for (int j = 0; j < 4; ++j) {
            int b = rbase + j;
            if (l == L - 1) out[((size_t)b * T + t) * H + g] = vv[j];
            if (t == T - 1)
                out[(size_t)B * T * H + ((size_t)(l * B + b)) * H + g] = vv[j];
        }
        VMWAIT(0);         // h (and out) stores drained; h at IF
        __syncthreads();   // BAR6: whole block done (also frees bufA reads)
        if (tid == 0) {
            unsigned val = (unsigned)(t + 1);
            unsigned* fp = flags + l * TILES_PER_L + rank;
            asm volatile("global_store_dword %0, %1, off sc0 sc1"
                         :: "v"(fp), "v"(val) : "memory");
        }

        // ---- shadow: x-projection for t+1 ----------------------------------
        if (t + 1 < T) {
            #pragma unroll
            for (int i = 0; i < 16; ++i) { accE[i] = 0.f; accO[i] = 0.f; }
            const char* xbn = (const char*)(xbf + (size_t)(t + 1) * B * IN);
            XSTAGE(xbn, 0, 0);
            __syncthreads();                        // BAR7
            MFMA_X(0, 0);
            XSTAGE(xbn, 1, BUFB);
            __syncthreads();                        // BAR8
            MFMA_X(1, BUFB);
        }
    }
}

// ---------------------------------------------------------------------------
extern "C" void kernel_launch(void* const* d_in, const int* in_sizes, int n_in,
                              void* d_out, int out_size, void* d_ws, size_t ws_size,
                              hipStream_t stream) {
    const float* x   = (const float*)d_in[0];
    const float* h0  = (const float*)d_in[1];
    const float* wih = (const float*)d_in[2];
    const float* whh = (const float*)d_in[3];
    const float* bih = (const float*)d_in[4];
    const float* bhh = (const float*)d_in[5];
    float* out = (float*)d_out;

    char* ws = (char*)d_ws;
    __bf16* xbf = (__bf16*)ws;                                   // 16 MB
    __bf16* hb0 = (__bf16*)(ws + (size_t)16777216);              // 768 KB
    __bf16* hb1 = (__bf16*)(ws + (size_t)16777216 + 786432);     // 768 KB
    unsigned* flags = (unsigned*)(ws + (size_t)16777216 + 2 * 786432); // 768 B

    (void)hipMemsetAsync(flags, 0, L * TILES_PER_L * sizeof(unsigned), stream);
    prep_kernel<<<2048, 256, 0, stream>>>(x, h0, xbf, hb0);

    rnn_kernel<<<NBLK, TPB, 0, stream>>>(
        xbf, wih, whh, bih, bhh, hb0, hb1, out, flags);
}